// Round 1
// baseline (12644.324 us; speedup 1.0000x reference)
//
#include <hip/hip_runtime.h>
#include <cstddef>

#define T_STEPS 80
#define BATCH   256
#define DIM     4936
#define EMB     200
#define DE      5136
#define HID     512
#define SIXH    3072
#define FIVEH   2560
#define NCLS    151
#define NPACK   15504

// ---------------------------------------------------------------------------
// Kernel 1: PX[m, n] = b_in[n] + sum_k X[m, k] * W_in[n, k]   (k < 4936)
// M = chunk*256 (mult of 128), N = 3072, K = 4936. Classic fp32 SGEMM,
// 128x128 tile, BK=16, 256 threads, 8x8 micro-tile.
// ---------------------------------------------------------------------------
__global__ __launch_bounds__(256) void px_gemm(
    const float* __restrict__ X,     // [M, 4936]
    const float* __restrict__ Win,   // [3072, 5136]
    const float* __restrict__ b_in,  // [3072]
    float* __restrict__ PX)          // [M, 3072]
{
    __shared__ float As[16][132];
    __shared__ float Bs[16][132];

    const int tid = threadIdx.x;
    const int tx  = tid & 15;
    const int ty  = tid >> 4;
    const int m0  = blockIdx.y * 128;
    const int n0  = blockIdx.x * 128;

    const int lrow = tid >> 1;        // 0..127
    const int lk   = (tid & 1) * 8;   // 0 or 8

    float acc[8][8];
#pragma unroll
    for (int i = 0; i < 8; ++i)
#pragma unroll
        for (int j = 0; j < 8; ++j) acc[i][j] = 0.f;

    for (int k0 = 0; k0 < DIM; k0 += 16) {
        // ---- load A, B slices into registers (guarded on K) ----
        float ar[8], br[8];
        const float* ap = X   + (size_t)(m0 + lrow) * DIM + k0 + lk;
        const float* bp = Win + (size_t)(n0 + lrow) * DE  + k0 + lk;
        if (k0 + lk + 7 < DIM) {
            float4 a0 = *(const float4*)(ap);
            float4 a1 = *(const float4*)(ap + 4);
            float4 b0 = *(const float4*)(bp);
            float4 b1 = *(const float4*)(bp + 4);
            ar[0]=a0.x; ar[1]=a0.y; ar[2]=a0.z; ar[3]=a0.w;
            ar[4]=a1.x; ar[5]=a1.y; ar[6]=a1.z; ar[7]=a1.w;
            br[0]=b0.x; br[1]=b0.y; br[2]=b0.z; br[3]=b0.w;
            br[4]=b1.x; br[5]=b1.y; br[6]=b1.z; br[7]=b1.w;
        } else {
#pragma unroll
            for (int j = 0; j < 8; ++j) {
                bool ok = (k0 + lk + j) < DIM;
                ar[j] = ok ? ap[j] : 0.f;
                br[j] = ok ? bp[j] : 0.f;
            }
        }
        __syncthreads();   // previous compute done reading LDS
#pragma unroll
        for (int j = 0; j < 8; ++j) {
            As[lk + j][lrow] = ar[j];
            Bs[lk + j][lrow] = br[j];
        }
        __syncthreads();   // tile ready

        // ---- compute ----
#pragma unroll
        for (int kk = 0; kk < 16; ++kk) {
            float4 a0 = *(const float4*)&As[kk][ty * 4];
            float4 a1 = *(const float4*)&As[kk][64 + ty * 4];
            float4 b0 = *(const float4*)&Bs[kk][tx * 4];
            float4 b1 = *(const float4*)&Bs[kk][64 + tx * 4];
            float av[8] = {a0.x,a0.y,a0.z,a0.w,a1.x,a1.y,a1.z,a1.w};
            float bv[8] = {b0.x,b0.y,b0.z,b0.w,b1.x,b1.y,b1.z,b1.w};
#pragma unroll
            for (int i = 0; i < 8; ++i)
#pragma unroll
                for (int j = 0; j < 8; ++j)
                    acc[i][j] = fmaf(av[i], bv[j], acc[i][j]);
        }
    }

    // ---- epilogue: add bias, store ----
    float bn[8];
#pragma unroll
    for (int j = 0; j < 4; ++j) {
        bn[j]     = b_in[n0 + tx * 4 + j];
        bn[4 + j] = b_in[n0 + 64 + tx * 4 + j];
    }
#pragma unroll
    for (int i = 0; i < 8; ++i) {
        int rm = m0 + ((i < 4) ? (ty * 4 + i) : (64 + ty * 4 + (i - 4)));
        float* crow = PX + (size_t)rm * SIXH + n0;
        float4 v0 = {acc[i][0] + bn[0], acc[i][1] + bn[1],
                     acc[i][2] + bn[2], acc[i][3] + bn[3]};
        float4 v1 = {acc[i][4] + bn[4], acc[i][5] + bn[5],
                     acc[i][6] + bn[6], acc[i][7] + bn[7]};
        *(float4*)(crow + tx * 4)      = v0;
        *(float4*)(crow + 64 + tx * 4) = v1;
    }
}

// ---------------------------------------------------------------------------
// Kernel 2 (per step): pi[b, n] = PX_t[b, n] + pe[b,:]@W_in[n, 4936:5136]
//                      ps[b, n] = b_state[n] + h[b,:]@W_state[n,:]
// 64x64 tiles over a 256 x (3072+2560) output; blockIdx.x < 48 -> pi part.
// ---------------------------------------------------------------------------
__global__ __launch_bounds__(256) void step_gemm(
    const float* __restrict__ Win,      // [3072, 5136]
    const float* __restrict__ Wstate,   // [2560, 512]
    const float* __restrict__ b_state,  // [2560]
    const float* __restrict__ pe,       // [256, 200]
    const float* __restrict__ h,        // [256, 512]
    const float* __restrict__ px_t,     // [256, 3072]
    float* __restrict__ pi,             // [256, 3072]
    float* __restrict__ ps)             // [256, 2560]
{
    __shared__ float As[16][68];
    __shared__ float Bs[16][68];

    const int tid = threadIdx.x;
    const int tx  = tid & 15;
    const int ty  = tid >> 4;
    const int bx  = blockIdx.x;
    const int m0  = blockIdx.y * 64;

    const bool isPi = (bx < 48);
    const float* A  = isPi ? pe : h;
    const int lda   = isPi ? EMB : HID;
    const int K     = isPi ? EMB : HID;
    const float* Bm = isPi ? (Win + DIM) : Wstate;
    const size_t ldb = isPi ? DE : HID;
    const int n0    = isPi ? bx * 64 : (bx - 48) * 64;

    const int lrow = tid >> 2;       // 0..63
    const int lk   = (tid & 3) * 4;  // 0,4,8,12

    float acc[4][4];
#pragma unroll
    for (int i = 0; i < 4; ++i)
#pragma unroll
        for (int j = 0; j < 4; ++j) acc[i][j] = 0.f;

    for (int k0 = 0; k0 < K; k0 += 16) {
        int k = k0 + lk;
        float4 av = {0.f,0.f,0.f,0.f}, bv = {0.f,0.f,0.f,0.f};
        if (k < K) {   // K % 4 == 0 so whole float4 valid
            av = *(const float4*)(A  + (size_t)(m0 + lrow) * lda + k);
            bv = *(const float4*)(Bm + (size_t)(n0 + lrow) * ldb + k);
        }
        __syncthreads();
        As[lk + 0][lrow] = av.x; As[lk + 1][lrow] = av.y;
        As[lk + 2][lrow] = av.z; As[lk + 3][lrow] = av.w;
        Bs[lk + 0][lrow] = bv.x; Bs[lk + 1][lrow] = bv.y;
        Bs[lk + 2][lrow] = bv.z; Bs[lk + 3][lrow] = bv.w;
        __syncthreads();
#pragma unroll
        for (int kk = 0; kk < 16; ++kk) {
            float4 a4 = *(const float4*)&As[kk][ty * 4];
            float4 b4 = *(const float4*)&Bs[kk][tx * 4];
            float avr[4] = {a4.x, a4.y, a4.z, a4.w};
            float bvr[4] = {b4.x, b4.y, b4.z, b4.w};
#pragma unroll
            for (int i = 0; i < 4; ++i)
#pragma unroll
                for (int j = 0; j < 4; ++j)
                    acc[i][j] = fmaf(avr[i], bvr[j], acc[i][j]);
        }
    }

#pragma unroll
    for (int i = 0; i < 4; ++i) {
        int m = m0 + ty * 4 + i;
        if (isPi) {
            float* dst = pi + (size_t)m * SIXH + n0 + tx * 4;
            const float* src = px_t + (size_t)m * SIXH + n0 + tx * 4;
#pragma unroll
            for (int j = 0; j < 4; ++j) dst[j] = src[j] + acc[i][j];
        } else {
            float* dst = ps + (size_t)m * FIVEH + n0 + tx * 4;
#pragma unroll
            for (int j = 0; j < 4; ++j) dst[j] = acc[i][j] + b_state[n0 + tx * 4 + j];
        }
    }
}

// ---------------------------------------------------------------------------
// Kernel 3 (per step): gates -> h_new, c_new; pred = h_new @ W_out.T + b_out;
// argmax over classes 1..150; commit + new prev_embed. One block per b.
// ---------------------------------------------------------------------------
__global__ __launch_bounds__(256) void step_update(
    const float* __restrict__ pi,      // [256, 3072]
    const float* __restrict__ ps,      // [256, 2560]
    const float* __restrict__ Wout,    // [151, 512]
    const float* __restrict__ b_out,   // [151]
    const float* __restrict__ embed,   // [152, 200]
    float* __restrict__ h,             // [256, 512]
    float* __restrict__ c,             // [256, 512]
    float* __restrict__ pe,            // [256, 200]
    float* __restrict__ dists_t,       // [256, 151]
    int*   __restrict__ commit_t)      // [256]
{
    __shared__ float hs[HID];
    __shared__ float preds[NCLS];
    __shared__ int   best_s;

    const int b   = blockIdx.x;
    const int tid = threadIdx.x;
    const float* pirow = pi + (size_t)b * SIXH;
    const float* psrow = ps + (size_t)b * FIVEH;

    for (int u = tid; u < HID; u += 256) {
        float i_g = 1.f / (1.f + expf(-(pirow[u]           + psrow[u])));
        float f_g = 1.f / (1.f + expf(-(pirow[HID + u]     + psrow[HID + u])));
        float m_i = tanhf(pirow[2 * HID + u] + psrow[2 * HID + u]);
        float o_g = 1.f / (1.f + expf(-(pirow[3 * HID + u] + psrow[3 * HID + u])));
        float c_new = i_g * m_i + f_g * c[(size_t)b * HID + u];
        float outv  = o_g * tanhf(c_new);
        float hw    = 1.f / (1.f + expf(-(pirow[4 * HID + u] + psrow[4 * HID + u])));
        float h_new = hw * outv + (1.f - hw) * pirow[5 * HID + u];
        c[(size_t)b * HID + u] = c_new;
        h[(size_t)b * HID + u] = h_new;
        hs[u] = h_new;
    }
    __syncthreads();

    if (tid < NCLS) {
        const float* wrow = Wout + (size_t)tid * HID;
        float s = b_out[tid];
#pragma unroll 8
        for (int k = 0; k < HID; ++k) s = fmaf(hs[k], wrow[k], s);
        preds[tid] = s;
        dists_t[(size_t)b * NCLS + tid] = s;
    }
    __syncthreads();

    if (tid == 0) {
        int   bi = 1;
        float bv = preds[1];
        for (int n = 2; n < NCLS; ++n) {
            float v = preds[n];
            if (v > bv) { bv = v; bi = n; }   // strict > keeps first max (jnp.argmax)
        }
        best_s = bi;
        commit_t[b] = bi;
    }
    __syncthreads();

    const float* erow = embed + (size_t)(best_s + 1) * EMB;
    for (int e = tid; e < EMB; e += 256) pe[(size_t)b * EMB + e] = erow[e];
}

// ---------------------------------------------------------------------------
// Kernel 4: packed gather into d_out. One block per packed row.
// ---------------------------------------------------------------------------
__global__ __launch_bounds__(192) void gather_out(
    const float* __restrict__ dists,    // [80*256, 151]
    const int*   __restrict__ commits,  // [80*256]
    const int*   __restrict__ gidx,     // [15504]
    float* __restrict__ out)
{
    const int i = blockIdx.x;
    const int g = gidx[i];
    if (threadIdx.x < NCLS)
        out[(size_t)i * NCLS + threadIdx.x] = dists[(size_t)g * NCLS + threadIdx.x];
    if (threadIdx.x == NCLS)
        out[(size_t)NPACK * NCLS + i] = (float)commits[g];
}

// ---------------------------------------------------------------------------
// Kernel 0: init h=0, c=0, pe[b,:]=embed[0,:]
// ---------------------------------------------------------------------------
__global__ __launch_bounds__(256) void init_state(
    float* __restrict__ h, float* __restrict__ c, float* __restrict__ pe,
    const float* __restrict__ embed)
{
    int i = blockIdx.x * 256 + threadIdx.x;
    if (i < BATCH * HID) { h[i] = 0.f; c[i] = 0.f; }
    if (i < BATCH * EMB) pe[i] = embed[i % EMB];
}

// ---------------------------------------------------------------------------
extern "C" void kernel_launch(void* const* d_in, const int* in_sizes, int n_in,
                              void* d_out, int out_size, void* d_ws, size_t ws_size,
                              hipStream_t stream)
{
    const float* X      = (const float*)d_in[0];  // [80,256,4936]
    const float* embed  = (const float*)d_in[1];  // [152,200]
    const float* Win    = (const float*)d_in[2];  // [3072,5136]
    const float* b_in   = (const float*)d_in[3];
    const float* Wst    = (const float*)d_in[4];  // [2560,512]
    const float* b_st   = (const float*)d_in[5];
    const float* Wout   = (const float*)d_in[6];  // [151,512]
    const float* b_out  = (const float*)d_in[7];
    const int*   gidx   = (const int*)d_in[8];

    float* ws  = (float*)d_ws;
    float* ps  = ws;                           // 256*2560
    float* pi  = ps + BATCH * FIVEH;           // 256*3072
    float* h   = pi + BATCH * SIXH;            // 256*512
    float* c   = h + BATCH * HID;              // 256*512
    float* pe  = c + BATCH * HID;              // 256*200
    int* commits = (int*)(pe + BATCH * EMB);   // 80*256
    float* dists = (float*)(commits + T_STEPS * BATCH);  // 80*256*151
    float* px  = dists + (size_t)T_STEPS * BATCH * NCLS;

    const size_t fixed_f = (size_t)(px - ws);
    const size_t chunk_f = (size_t)BATCH * SIXH;   // floats per timestep of PX
    size_t availf = ws_size / sizeof(float);
    int CT = 1;
    if (availf > fixed_f + chunk_f) {
        size_t c2 = (availf - fixed_f) / chunk_f;
        CT = (int)(c2 > T_STEPS ? T_STEPS : c2);
    }

    init_state<<<512, 256, 0, stream>>>(h, c, pe, embed);

    for (int t0 = 0; t0 < T_STEPS; t0 += CT) {
        int nt = T_STEPS - t0;
        if (nt > CT) nt = CT;
        dim3 g(SIXH / 128, nt * BATCH / 128);
        px_gemm<<<g, 256, 0, stream>>>(X + (size_t)t0 * BATCH * DIM, Win, b_in, px);
        for (int t = t0; t < t0 + nt; ++t) {
            step_gemm<<<dim3(88, 4), 256, 0, stream>>>(
                Win, Wst, b_st, pe, h, px + (size_t)(t - t0) * BATCH * SIXH, pi, ps);
            step_update<<<BATCH, 256, 0, stream>>>(
                pi, ps, Wout, b_out, embed, h, c, pe,
                dists + (size_t)t * BATCH * NCLS, commits + (size_t)t * BATCH);
        }
    }

    gather_out<<<NPACK, 192, 0, stream>>>(dists, commits, gidx, (float*)d_out);
}

// Round 2
// 5732.930 us; speedup vs baseline: 2.2056x; 2.2056x over previous
//
#include <hip/hip_runtime.h>
#include <cstddef>
#include <cstdint>

#define T_STEPS 80
#define BATCH   256
#define DIM     4936
#define EMB     200
#define DE      5136
#define HID     512
#define SIXH    3072
#define FIVEH   2560
#define NCLS    151
#define NPACK   15504
#define NKT     156          // ceil(4936/32) -> Kpad = 4992

typedef unsigned short ushort_t;
typedef short short8 __attribute__((ext_vector_type(8)));
typedef float f32x4 __attribute__((ext_vector_type(4)));

__device__ inline ushort_t f2bf_rn(float x) {
    union { float f; uint32_t u; } v; v.f = x;
    uint32_t u = v.u;
    return (ushort_t)((u + 0x7FFFu + ((u >> 16) & 1u)) >> 16);
}
__device__ inline float bf2f(ushort_t b) {
    union { float f; uint32_t u; } v; v.u = ((uint32_t)b) << 16;
    return v.f;
}
__device__ inline float sigmoidf(float x) { return 1.f / (1.f + expf(-x)); }

// ---------------------------------------------------------------------------
// convert_split: src [ntiles*128 rows, ld] fp32 -> hi/lo bf16 in tiled layout
// out[tile][ktile][kb(4)][row(128)][8]   (zero-padded for k >= kvalid)
// ---------------------------------------------------------------------------
__global__ __launch_bounds__(256) void convert_split(
    const float* __restrict__ src, int ld, int kvalid,
    ushort_t* __restrict__ hi, ushort_t* __restrict__ lo, int nktiles)
{
    __shared__ float s[128][33];
    const int tid = threadIdx.x;
    const int kt  = blockIdx.x;
    const int mt  = blockIdx.y;

#pragma unroll
    for (int it = 0; it < 4; ++it) {
        int idx = it * 256 + tid;          // 1024 float4 slots
        int row = idx >> 3;
        int f4  = idx & 7;
        int k   = kt * 32 + f4 * 4;
        const float* p = src + (size_t)(mt * 128 + row) * ld + k;
        float4 v;
        if (k + 3 < kvalid) v = *(const float4*)p;
        else {
            v.x = (k + 0) < kvalid ? p[0] : 0.f;
            v.y = (k + 1) < kvalid ? p[1] : 0.f;
            v.z = (k + 2) < kvalid ? p[2] : 0.f;
            v.w = (k + 3) < kvalid ? p[3] : 0.f;
        }
        s[row][f4 * 4 + 0] = v.x; s[row][f4 * 4 + 1] = v.y;
        s[row][f4 * 4 + 2] = v.z; s[row][f4 * 4 + 3] = v.w;
    }
    __syncthreads();

    const size_t base = ((size_t)mt * nktiles + kt) * 4096;
#pragma unroll
    for (int it = 0; it < 2; ++it) {
        int o   = it * 256 + tid;          // 512 chunks of 8 ushorts
        int kb  = o >> 7;
        int row = o & 127;
        alignas(16) ushort_t hbuf[8];
        alignas(16) ushort_t lbuf[8];
#pragma unroll
        for (int e = 0; e < 8; ++e) {
            float x = s[row][kb * 8 + e];
            ushort_t hh = f2bf_rn(x);
            float lof = x - bf2f(hh);
            hbuf[e] = hh;
            lbuf[e] = f2bf_rn(lof);
        }
        *(uint4*)(hi + base + (size_t)o * 8) = *(const uint4*)hbuf;
        *(uint4*)(lo + base + (size_t)o * 8) = *(const uint4*)lbuf;
    }
}

// ---------------------------------------------------------------------------
// px_mfma: PX[m,n] = b_in[n] + sum_k X[m,k]*Win[n,k] via 3-term split bf16.
// 128x128 tile, BK=32, 4 waves, each wave 64x64 (4x4 frags of 16x16x32).
// A/B staged with global_load_lds (16B), layout [kb][row][8] -> conflict-free.
// ---------------------------------------------------------------------------
__device__ inline void gload16(const ushort_t* g, ushort_t* l) {
    __builtin_amdgcn_global_load_lds(
        (const __attribute__((address_space(1))) void*)g,
        (__attribute__((address_space(3))) void*)l, 16, 0, 0);
}

__global__ __launch_bounds__(256) void px_mfma(
    const ushort_t* __restrict__ Ah, const ushort_t* __restrict__ Al,
    const ushort_t* __restrict__ Bh, const ushort_t* __restrict__ Bl,
    const float* __restrict__ b_in, float* __restrict__ PX)
{
    __shared__ ushort_t sAh[4096], sAl[4096], sBh[4096], sBl[4096]; // 32 KiB

    const int tid  = threadIdx.x;
    const int wave = tid >> 6;
    const int lane = tid & 63;
    const int mt = blockIdx.y, nt = blockIdx.x;
    const int wr = wave >> 1, wc = wave & 1;

    f32x4 acc[4][4];
#pragma unroll
    for (int i = 0; i < 4; ++i)
#pragma unroll
        for (int j = 0; j < 4; ++j) acc[i][j] = (f32x4){0.f, 0.f, 0.f, 0.f};

    const size_t abase = (size_t)mt * NKT * 4096;
    const size_t bbase = (size_t)nt * NKT * 4096;
    const int lw = wave * 512;       // lds ushort offset for this wave, callsite 0
    const int kb = lane >> 4;
    const int lr = lane & 15;
    const int aoff = kb * 1024 + (wr * 64 + lr) * 8;
    const int boff = kb * 1024 + (wc * 64 + lr) * 8;

    for (int kt = 0; kt < NKT; ++kt) {
        const size_t ko = (size_t)kt * 4096 + tid * 8;
        gload16(Ah + abase + ko,        &sAh[lw]);
        gload16(Ah + abase + ko + 2048, &sAh[2048 + lw]);
        gload16(Al + abase + ko,        &sAl[lw]);
        gload16(Al + abase + ko + 2048, &sAl[2048 + lw]);
        gload16(Bh + bbase + ko,        &sBh[lw]);
        gload16(Bh + bbase + ko + 2048, &sBh[2048 + lw]);
        gload16(Bl + bbase + ko,        &sBl[lw]);
        gload16(Bl + bbase + ko + 2048, &sBl[2048 + lw]);
        __syncthreads();   // drains vmcnt -> staged data visible

        short8 ah[4], al[4], bh[4], bl[4];
#pragma unroll
        for (int i = 0; i < 4; ++i) {
            ah[i] = *(const short8*)&sAh[aoff + i * 128];
            al[i] = *(const short8*)&sAl[aoff + i * 128];
        }
#pragma unroll
        for (int j = 0; j < 4; ++j) {
            bh[j] = *(const short8*)&sBh[boff + j * 128];
            bl[j] = *(const short8*)&sBl[boff + j * 128];
        }
#pragma unroll
        for (int i = 0; i < 4; ++i)
#pragma unroll
            for (int j = 0; j < 4; ++j) {
                acc[i][j] = __builtin_amdgcn_mfma_f32_16x16x32_bf16(ah[i], bh[j], acc[i][j], 0, 0, 0);
                acc[i][j] = __builtin_amdgcn_mfma_f32_16x16x32_bf16(ah[i], bl[j], acc[i][j], 0, 0, 0);
                acc[i][j] = __builtin_amdgcn_mfma_f32_16x16x32_bf16(al[i], bh[j], acc[i][j], 0, 0, 0);
            }
        __syncthreads();   // all waves done reading before next stage overwrites
    }

#pragma unroll
    for (int i = 0; i < 4; ++i) {
        const int row = mt * 128 + wr * 64 + i * 16 + (lane >> 4) * 4;
#pragma unroll
        for (int j = 0; j < 4; ++j) {
            const int col = nt * 128 + wc * 64 + j * 16 + (lane & 15);
            const float bias = b_in[col];
#pragma unroll
            for (int r = 0; r < 4; ++r)
                PX[(size_t)(row + r) * SIXH + col] = acc[i][j][r] + bias;
        }
    }
}

// ---------------------------------------------------------------------------
// ew_gemm: EW[m,n] = sum_k embed[m,k] * Win[n, 4936+k]   (m<152, K=200)
// ---------------------------------------------------------------------------
__global__ __launch_bounds__(256) void ew_gemm(
    const float* __restrict__ embed, const float* __restrict__ Win,
    float* __restrict__ EW)
{
    __shared__ float As[16][68];
    __shared__ float Bs[16][68];
    const int tid = threadIdx.x;
    const int tx  = tid & 15;
    const int ty  = tid >> 4;
    const int n0  = blockIdx.x * 64;
    const int m0  = blockIdx.y * 64;
    const int lrow = tid >> 2;
    const int lk   = (tid & 3) * 4;

    float acc[4][4];
#pragma unroll
    for (int i = 0; i < 4; ++i)
#pragma unroll
        for (int j = 0; j < 4; ++j) acc[i][j] = 0.f;

    for (int k0 = 0; k0 < EMB; k0 += 16) {
        int k = k0 + lk;
        float4 av = {0.f,0.f,0.f,0.f}, bv = {0.f,0.f,0.f,0.f};
        if (k < EMB) {
            int am = m0 + lrow;
            if (am < 152) av = *(const float4*)(embed + (size_t)am * EMB + k);
            bv = *(const float4*)(Win + (size_t)(n0 + lrow) * DE + DIM + k);
        }
        __syncthreads();
        As[lk + 0][lrow] = av.x; As[lk + 1][lrow] = av.y;
        As[lk + 2][lrow] = av.z; As[lk + 3][lrow] = av.w;
        Bs[lk + 0][lrow] = bv.x; Bs[lk + 1][lrow] = bv.y;
        Bs[lk + 2][lrow] = bv.z; Bs[lk + 3][lrow] = bv.w;
        __syncthreads();
#pragma unroll
        for (int kk = 0; kk < 16; ++kk) {
            float4 a4 = *(const float4*)&As[kk][ty * 4];
            float4 b4 = *(const float4*)&Bs[kk][tx * 4];
            float avr[4] = {a4.x, a4.y, a4.z, a4.w};
            float bvr[4] = {b4.x, b4.y, b4.z, b4.w};
#pragma unroll
            for (int i = 0; i < 4; ++i)
#pragma unroll
                for (int j = 0; j < 4; ++j)
                    acc[i][j] = fmaf(avr[i], bvr[j], acc[i][j]);
        }
    }
#pragma unroll
    for (int i = 0; i < 4; ++i) {
        int m = m0 + ty * 4 + i;
        if (m < 152) {
#pragma unroll
            for (int j = 0; j < 4; ++j)
                EW[(size_t)m * SIXH + n0 + tx * 4 + j] = acc[i][j];
        }
    }
}

// ---------------------------------------------------------------------------
// ps_gemm: ps = h @ Wst.T + b_state   [256 x 2560], K=512, fp32
// ---------------------------------------------------------------------------
__global__ __launch_bounds__(256) void ps_gemm(
    const float* __restrict__ Wst, const float* __restrict__ b_state,
    const float* __restrict__ h, float* __restrict__ ps)
{
    __shared__ float As[16][68];
    __shared__ float Bs[16][68];
    const int tid = threadIdx.x;
    const int tx  = tid & 15;
    const int ty  = tid >> 4;
    const int n0  = blockIdx.x * 64;
    const int m0  = blockIdx.y * 64;
    const int lrow = tid >> 2;
    const int lk   = (tid & 3) * 4;

    float acc[4][4];
#pragma unroll
    for (int i = 0; i < 4; ++i)
#pragma unroll
        for (int j = 0; j < 4; ++j) acc[i][j] = 0.f;

    for (int k0 = 0; k0 < HID; k0 += 16) {
        float4 av = *(const float4*)(h   + (size_t)(m0 + lrow) * HID + k0 + lk);
        float4 bv = *(const float4*)(Wst + (size_t)(n0 + lrow) * HID + k0 + lk);
        __syncthreads();
        As[lk + 0][lrow] = av.x; As[lk + 1][lrow] = av.y;
        As[lk + 2][lrow] = av.z; As[lk + 3][lrow] = av.w;
        Bs[lk + 0][lrow] = bv.x; Bs[lk + 1][lrow] = bv.y;
        Bs[lk + 2][lrow] = bv.z; Bs[lk + 3][lrow] = bv.w;
        __syncthreads();
#pragma unroll
        for (int kk = 0; kk < 16; ++kk) {
            float4 a4 = *(const float4*)&As[kk][ty * 4];
            float4 b4 = *(const float4*)&Bs[kk][tx * 4];
            float avr[4] = {a4.x, a4.y, a4.z, a4.w};
            float bvr[4] = {b4.x, b4.y, b4.z, b4.w};
#pragma unroll
            for (int i = 0; i < 4; ++i)
#pragma unroll
                for (int j = 0; j < 4; ++j)
                    acc[i][j] = fmaf(avr[i], bvr[j], acc[i][j]);
        }
    }
#pragma unroll
    for (int i = 0; i < 4; ++i) {
        int m = m0 + ty * 4 + i;
        float* dst = ps + (size_t)m * FIVEH + n0 + tx * 4;
#pragma unroll
        for (int j = 0; j < 4; ++j) dst[j] = acc[i][j] + b_state[n0 + tx * 4 + j];
    }
}

// ---------------------------------------------------------------------------
// step_update: gates -> h,c; pred = h@Wout.T + b_out; argmax -> commit.
// pi = px_t + EW[prev_commit+1] folded in here (no pe vector anymore).
// ---------------------------------------------------------------------------
__global__ __launch_bounds__(256) void step_update(
    const float* __restrict__ px_t,        // [256, 3072]
    const float* __restrict__ EW,          // [152, 3072]
    const float* __restrict__ ps,          // [256, 2560]
    const int*   __restrict__ commit_prev, // [256] (prev step) or unused
    int first,
    const float* __restrict__ Wout, const float* __restrict__ b_out,
    float* __restrict__ h, float* __restrict__ c,
    float* __restrict__ dists_t, int* __restrict__ commit_t)
{
    __shared__ float hs[HID];
    __shared__ float preds[NCLS];

    const int b   = blockIdx.x;
    const int tid = threadIdx.x;
    const int erow = first ? 0 : (commit_prev[b] + 1);
    const float* ew  = EW + (size_t)erow * SIXH;
    const float* px  = px_t + (size_t)b * SIXH;
    const float* psr = ps + (size_t)b * FIVEH;

    for (int u = tid; u < HID; u += 256) {
        float p0 = px[u]           + ew[u]           + psr[u];
        float p1 = px[HID + u]     + ew[HID + u]     + psr[HID + u];
        float p2 = px[2*HID + u]   + ew[2*HID + u]   + psr[2*HID + u];
        float p3 = px[3*HID + u]   + ew[3*HID + u]   + psr[3*HID + u];
        float p4 = px[4*HID + u]   + ew[4*HID + u]   + psr[4*HID + u];
        float p5 = px[5*HID + u]   + ew[5*HID + u];
        float i_g = sigmoidf(p0);
        float f_g = sigmoidf(p1);
        float m_i = tanhf(p2);
        float o_g = sigmoidf(p3);
        float c_new = i_g * m_i + f_g * c[(size_t)b * HID + u];
        float outv  = o_g * tanhf(c_new);
        float hw    = sigmoidf(p4);
        float h_new = hw * outv + (1.f - hw) * p5;
        c[(size_t)b * HID + u] = c_new;
        h[(size_t)b * HID + u] = h_new;
        hs[u] = h_new;
    }
    __syncthreads();

    if (tid < NCLS) {
        const float* w = Wout + (size_t)tid * HID;
        float s0 = 0.f, s1 = 0.f, s2 = 0.f, s3 = 0.f;
        for (int k = 0; k < HID; k += 4) {
            s0 = fmaf(hs[k + 0], w[k + 0], s0);
            s1 = fmaf(hs[k + 1], w[k + 1], s1);
            s2 = fmaf(hs[k + 2], w[k + 2], s2);
            s3 = fmaf(hs[k + 3], w[k + 3], s3);
        }
        float s = b_out[tid] + ((s0 + s1) + (s2 + s3));
        preds[tid] = s;
        dists_t[(size_t)b * NCLS + tid] = s;
    }
    __syncthreads();

    if (tid == 0) {
        int   bi = 1;
        float bv = preds[1];
        for (int n = 2; n < NCLS; ++n) {
            float v = preds[n];
            if (v > bv) { bv = v; bi = n; }
        }
        commit_t[b] = bi;
    }
}

// ---------------------------------------------------------------------------
__global__ __launch_bounds__(192) void gather_out(
    const float* __restrict__ dists, const int* __restrict__ commits,
    const int* __restrict__ gidx, float* __restrict__ out)
{
    const int i = blockIdx.x;
    const int g = gidx[i];
    if (threadIdx.x < NCLS)
        out[(size_t)i * NCLS + threadIdx.x] = dists[(size_t)g * NCLS + threadIdx.x];
    if (threadIdx.x == NCLS)
        out[(size_t)NPACK * NCLS + i] = (float)commits[g];
}

__global__ __launch_bounds__(256) void init_state(float* __restrict__ h, float* __restrict__ c)
{
    int i = blockIdx.x * 256 + threadIdx.x;
    if (i < BATCH * HID) { h[i] = 0.f; c[i] = 0.f; }
}

// ---------------------------------------------------------------------------
extern "C" void kernel_launch(void* const* d_in, const int* in_sizes, int n_in,
                              void* d_out, int out_size, void* d_ws, size_t ws_size,
                              hipStream_t stream)
{
    const float* X      = (const float*)d_in[0];  // [80,256,4936]
    const float* embed  = (const float*)d_in[1];  // [152,200]
    const float* Win    = (const float*)d_in[2];  // [3072,5136]
    const float* b_in   = (const float*)d_in[3];
    const float* Wst    = (const float*)d_in[4];  // [2560,512]
    const float* b_st   = (const float*)d_in[5];
    const float* Wout   = (const float*)d_in[6];  // [151,512]
    const float* b_out  = (const float*)d_in[7];
    const int*   gidx   = (const int*)d_in[8];

    const size_t WN = (size_t)24 * NKT * 4096;    // ushorts per W array
    ushort_t* Wh = (ushort_t*)d_ws;
    ushort_t* Wl = Wh + WN;
    float* EW    = (float*)(Wl + WN);
    float* ps    = EW + (size_t)152 * SIXH;
    float* h     = ps + (size_t)BATCH * FIVEH;
    float* c     = h + (size_t)BATCH * HID;
    float* dists = c + (size_t)BATCH * HID;
    int* commits = (int*)(dists + (size_t)T_STEPS * BATCH * NCLS);
    char* cbase  = (char*)(commits + T_STEPS * BATCH);

    size_t off = (size_t)(cbase - (char*)d_ws);
    off = (off + 255) & ~(size_t)255;
    const size_t per_t = (size_t)2 * 2 * NKT * 4096 * 2 + (size_t)BATCH * SIXH * 4;
    size_t rem = (ws_size > off) ? (ws_size - off) : 0;
    int CT = (int)(rem / per_t);
    if (CT > T_STEPS) CT = T_STEPS;
    if (CT < 1) CT = 1;

    ushort_t* Xh = (ushort_t*)((char*)d_ws + off);
    ushort_t* Xl = Xh + (size_t)2 * CT * NKT * 4096;
    float* px    = (float*)(Xl + (size_t)2 * CT * NKT * 4096);

    // one-time prep
    convert_split<<<dim3(NKT, 24), 256, 0, stream>>>(Win, DE, DIM, Wh, Wl, NKT);
    ew_gemm<<<dim3(SIXH / 64, 3), 256, 0, stream>>>(embed, Win, EW);
    init_state<<<512, 256, 0, stream>>>(h, c);

    for (int t0 = 0; t0 < T_STEPS; t0 += CT) {
        int nt = T_STEPS - t0;
        if (nt > CT) nt = CT;
        convert_split<<<dim3(NKT, 2 * nt), 256, 0, stream>>>(
            X + (size_t)t0 * BATCH * DIM, DIM, DIM, Xh, Xl, NKT);
        px_mfma<<<dim3(SIXH / 128, 2 * nt), 256, 0, stream>>>(
            Xh, Xl, Wh, Wl, b_in, px);
        for (int t = t0; t < t0 + nt; ++t) {
            ps_gemm<<<dim3(FIVEH / 64, BATCH / 64), 256, 0, stream>>>(Wst, b_st, h, ps);
            step_update<<<BATCH, 256, 0, stream>>>(
                px + (size_t)(t - t0) * BATCH * SIXH, EW, ps,
                commits + (size_t)(t > 0 ? t - 1 : 0) * BATCH, (t == 0) ? 1 : 0,
                Wout, b_out, h, c,
                dists + (size_t)t * BATCH * NCLS, commits + (size_t)t * BATCH);
        }
    }

    gather_out<<<NPACK, 192, 0, stream>>>(dists, commits, gidx, (float*)d_out);
}